// Round 2
// baseline (773.845 us; speedup 1.0000x reference)
//
#include <hip/hip_runtime.h>

#define DD 256
#define TWO_D 512
#define NLAYER 5
#define NGRAPH 256
#define BNEPS 1e-5f

typedef __attribute__((ext_vector_type(8))) _Float16 half8;
typedef __attribute__((ext_vector_type(4))) _Float16 half4;
typedef __attribute__((ext_vector_type(4))) float f32x4;
typedef __attribute__((address_space(1))) void gvoid_t;
typedef __attribute__((address_space(3))) void svoid_t;

// ---------------- embedding (+ zero deg) ----------------
__global__ __launch_bounds__(256) void embed_kernel(
    const int* __restrict__ xf,
    const float* __restrict__ nt1, const float* __restrict__ nt2,
    const float* __restrict__ nt3, const float* __restrict__ nt4,
    const float* __restrict__ nt5, const float* __restrict__ nt6,
    float* __restrict__ h, int* __restrict__ deg, int N)
{
  int i = blockIdx.x;
  int j = threadIdx.x;
  if (i >= N) return;
  if (j == 0) deg[i] = 0;
  int x0 = xf[i*6+0], x1 = xf[i*6+1], x2 = xf[i*6+2];
  int x3 = xf[i*6+3], x4 = xf[i*6+4], x5 = xf[i*6+5];
  float v = nt1[x0*DD+j] + nt2[x1*DD+j] + nt3[x2*DD+j]
          + nt4[x3*DD+j] + nt5[x4*DD+j] + nt6[x5*DD+j];
  h[(size_t)i*DD + j] = v;
}

// ---------------- CSR build ----------------
__global__ __launch_bounds__(256) void hist_pack_kernel(
    const int* __restrict__ ei, const int* __restrict__ ea,
    int* __restrict__ deg, int* __restrict__ packed, int E)
{
  int e = blockIdx.x*256 + threadIdx.x;
  if (e >= E) return;
  int src = ei[e];
  int dst = ei[E + e];
  int code = (ea[e*5+0]&1) | ((ea[e*5+1]&1)<<1) | ((ea[e*5+2]&1)<<2)
           | ((ea[e*5+3]&1)<<3) | ((ea[e*5+4]&1)<<4);
  packed[e] = src | (code << 16);
  atomicAdd(&deg[dst], 1);
}

__global__ __launch_bounds__(1024) void scan_kernel(
    const int* __restrict__ deg, int* __restrict__ row_start,
    int* __restrict__ cursor, int N)
{
  __shared__ int sh[1024];
  __shared__ int carry_s;
  int t = threadIdx.x;
  if (t == 0) carry_s = 0;
  __syncthreads();
  for (int base = 0; base < N; base += 1024) {
    int carry = carry_s;
    int idx = base + t;
    int v = (idx < N) ? deg[idx] : 0;
    sh[t] = v;
    __syncthreads();
    for (int off = 1; off < 1024; off <<= 1) {
      int x = (t >= off) ? sh[t - off] : 0;
      __syncthreads();
      sh[t] += x;
      __syncthreads();
    }
    int incl = sh[t];
    if (idx < N) { int ex = carry + incl - v; row_start[idx] = ex; cursor[idx] = ex; }
    __syncthreads();
    if (t == 1023) carry_s = carry + sh[1023];
    __syncthreads();
  }
  if (t == 0) row_start[N] = carry_s;
}

__global__ __launch_bounds__(256) void scatter_kernel(
    const int* __restrict__ ei, const int* __restrict__ packed,
    int* __restrict__ cursor, int* __restrict__ esort, int E)
{
  int e = blockIdx.x*256 + threadIdx.x;
  if (e >= E) return;
  int dst = ei[E + e];
  int pos = atomicAdd(&cursor[dst], 1);
  esort[pos] = packed[e];
}

// ---------------- weight fp16 + edge-table precompute ----------------
__global__ __launch_bounds__(256) void wconv_kernel(
    const float* __restrict__ w1, const float* __restrict__ w2,
    _Float16* __restrict__ w1h, _Float16* __restrict__ w2h, int n)
{
  for (int i = blockIdx.x*256 + threadIdx.x; i < n; i += gridDim.x*256) {
    w1h[i] = (_Float16)w1[i];
    w2h[i] = (_Float16)w2[i];
  }
}

__global__ __launch_bounds__(256) void etab_kernel(
    const float* __restrict__ et1, const float* __restrict__ et2,
    const float* __restrict__ et3, const float* __restrict__ et4,
    const float* __restrict__ et5, float* __restrict__ etab)
{
  int b = blockIdx.x;
  int l = b / 33, c = b % 33;
  int j = threadIdx.x;
  int a0 = (c==32)?4:(c&1);
  int a1 = (c==32)?0:((c>>1)&1);
  int a2 = (c==32)?0:((c>>2)&1);
  int a3 = (c==32)?0:((c>>3)&1);
  int a4 = (c==32)?0:((c>>4)&1);
  etab[((size_t)l*33 + c)*DD + j] =
      et1[(l*5+a0)*DD+j] + et2[(l*4+a1)*DD+j] + et3[(l*2+a2)*DD+j]
    + et4[(l*2+a3)*DD+j] + et5[(l*2+a4)*DD+j];
}

// ---------------- aggregation: one wave per node (CSR gather) ----------------
__global__ __launch_bounds__(256) void aggr_kernel(
    const float* __restrict__ h, const float* __restrict__ etab_l,
    const int* __restrict__ row_start, const int* __restrict__ esort,
    _Float16* __restrict__ aggrh, float* __restrict__ stats, int N)
{
  __shared__ __attribute__((aligned(16))) float se[33*DD];
  for (int i = threadIdx.x; i < 33*DD; i += 256) se[i] = etab_l[i];
  if (blockIdx.x == 0) { stats[threadIdx.x] = 0.f; stats[DD + threadIdx.x] = 0.f; }
  __syncthreads();
  const int wave = threadIdx.x >> 6, lane = threadIdx.x & 63;
  const int c4 = lane << 2;
  const int W0 = blockIdx.x*4 + wave, NW = gridDim.x*4;
  for (int node = W0; node < N; node += NW) {
    int p  = row_start[node];
    int pe = row_start[node+1];
    const float4 hv = *(const float4*)(h + (size_t)node*DD + c4);
    const float4 sv = *(const float4*)(se + 32*DD + c4);
    float ax = hv.x + sv.x, ay = hv.y + sv.y, az = hv.z + sv.z, aw = hv.w + sv.w;
    for (; p + 4 <= pe; p += 4) {
      int pk0 = esort[p], pk1 = esort[p+1], pk2 = esort[p+2], pk3 = esort[p+3];
      const float4 h0 = *(const float4*)(h + (size_t)(pk0 & 0xffff)*DD + c4);
      const float4 h1 = *(const float4*)(h + (size_t)(pk1 & 0xffff)*DD + c4);
      const float4 h2 = *(const float4*)(h + (size_t)(pk2 & 0xffff)*DD + c4);
      const float4 h3 = *(const float4*)(h + (size_t)(pk3 & 0xffff)*DD + c4);
      const float4 e0 = *(const float4*)(se + (pk0 >> 16)*DD + c4);
      const float4 e1 = *(const float4*)(se + (pk1 >> 16)*DD + c4);
      const float4 e2 = *(const float4*)(se + (pk2 >> 16)*DD + c4);
      const float4 e3 = *(const float4*)(se + (pk3 >> 16)*DD + c4);
      ax += (h0.x+e0.x) + (h1.x+e1.x) + (h2.x+e2.x) + (h3.x+e3.x);
      ay += (h0.y+e0.y) + (h1.y+e1.y) + (h2.y+e2.y) + (h3.y+e3.y);
      az += (h0.z+e0.z) + (h1.z+e1.z) + (h2.z+e2.z) + (h3.z+e3.z);
      aw += (h0.w+e0.w) + (h1.w+e1.w) + (h2.w+e2.w) + (h3.w+e3.w);
    }
    for (; p < pe; ++p) {
      int pk = esort[p];
      const float4 hx = *(const float4*)(h + (size_t)(pk & 0xffff)*DD + c4);
      const float4 ex = *(const float4*)(se + (pk >> 16)*DD + c4);
      ax += hx.x + ex.x; ay += hx.y + ex.y; az += hx.z + ex.z; aw += hx.w + ex.w;
    }
    half4 o;
    o.x = (_Float16)ax; o.y = (_Float16)ay; o.z = (_Float16)az; o.w = (_Float16)aw;
    *(half4*)(aggrh + (size_t)node*DD + c4) = o;
  }
}

// ---------------- fp16 MFMA GEMM: C[M,Nw] = A[M,K] * B[Nw,K]^T + bias ----------------
// MODE 0: fp16 out + relu.  MODE 1: f32 out + column stats (rows < Nreal).
template<int MODE>
__global__ __launch_bounds__(256) void gemm_bt(
    const _Float16* __restrict__ A,
    const _Float16* __restrict__ B,
    const float* __restrict__ bias,
    void* __restrict__ Cout,
    float* __restrict__ stats,
    int K, int Nw, int Nreal)
{
  __shared__ __attribute__((aligned(16))) _Float16 lA[128*32];
  __shared__ __attribute__((aligned(16))) _Float16 lB[128*32];
  const int NT = Nw >> 7;
  const int bm = blockIdx.x / NT, bn = blockIdx.x % NT;
  const int m0 = bm << 7, n0 = bn << 7;
  const int t = threadIdx.x;
  const int wave = t >> 6, lane = t & 63;
  const int wm = wave & 1, wn = wave >> 1;
  const int r15 = lane & 15, quad = lane >> 4;
  const int srow = lane >> 2, sq = (lane & 3) << 3;
  f32x4 acc[4][4] = {};
  for (int k0 = 0; k0 < K; k0 += 32) {
    __syncthreads();
#pragma unroll
    for (int i = 0; i < 2; ++i) {
      const int seg = wave*2 + i;
      const int row = seg*16 + srow;
      __builtin_amdgcn_global_load_lds((gvoid_t*)(A + (size_t)(m0+row)*K + k0 + sq),
                                       (svoid_t*)(lA + seg*512), 16, 0, 0);
      __builtin_amdgcn_global_load_lds((gvoid_t*)(B + (size_t)(n0+row)*K + k0 + sq),
                                       (svoid_t*)(lB + seg*512), 16, 0, 0);
    }
    __syncthreads();
    half8 af[4], bfr[4];
#pragma unroll
    for (int f = 0; f < 4; ++f) {
      af[f]  = *(const half8*)(lA + (((wm<<6) + (f<<4) + r15) << 5) + (quad<<3));
      bfr[f] = *(const half8*)(lB + (((wn<<6) + (f<<4) + r15) << 5) + (quad<<3));
    }
#pragma unroll
    for (int fm = 0; fm < 4; ++fm)
#pragma unroll
      for (int fn = 0; fn < 4; ++fn)
        acc[fm][fn] = __builtin_amdgcn_mfma_f32_16x16x32_f16(af[fm], bfr[fn], acc[fm][fn], 0, 0, 0);
  }
  if (MODE == 0) {
    _Float16* O = (_Float16*)Cout;
#pragma unroll
    for (int fn = 0; fn < 4; ++fn) {
      const int col = n0 + (wn<<6) + (fn<<4) + r15;
      const float bv = bias[col];
#pragma unroll
      for (int fm = 0; fm < 4; ++fm) {
        const int rowb = m0 + (wm<<6) + (fm<<4) + (quad<<2);
#pragma unroll
        for (int r = 0; r < 4; ++r) {
          float v = fmaxf(acc[fm][fn][r] + bv, 0.f);
          O[(size_t)(rowb + r)*Nw + col] = (_Float16)v;
        }
      }
    }
  } else {
    float* O = (float*)Cout;
#pragma unroll
    for (int fn = 0; fn < 4; ++fn) {
      const int col = n0 + (wn<<6) + (fn<<4) + r15;
      const float bv = bias[col];
      float s1 = 0.f, s2 = 0.f;
#pragma unroll
      for (int fm = 0; fm < 4; ++fm) {
        const int rowb = m0 + (wm<<6) + (fm<<4) + (quad<<2);
#pragma unroll
        for (int r = 0; r < 4; ++r) {
          float v = acc[fm][fn][r] + bv;
          O[(size_t)(rowb + r)*Nw + col] = v;
          if (rowb + r < Nreal) { s1 += v; s2 += v*v; }
        }
      }
      s1 += __shfl_xor(s1, 16); s1 += __shfl_xor(s1, 32);
      s2 += __shfl_xor(s2, 16); s2 += __shfl_xor(s2, 32);
      if (lane < 16) { atomicAdd(&stats[col], s1); atomicAdd(&stats[DD + col], s2); }
    }
  }
}

// ---------------- BN + ReLU over N rows ----------------
__global__ __launch_bounds__(256) void bn_relu_kernel(
    const float* __restrict__ hh, const float* __restrict__ stats,
    const float* __restrict__ g, const float* __restrict__ b,
    float* __restrict__ h, int N)
{
  int j = threadIdx.x;
  float inv_n = 1.0f / (float)N;
  float m  = stats[j] * inv_n;
  float var = fmaxf(stats[DD + j] * inv_n - m*m, 0.f);
  float sc = g[j] * rsqrtf(var + BNEPS);
  float sh = b[j] - m*sc;
  int r0 = blockIdx.x * 64;
  for (int r = 0; r < 64; ++r) {
    int row = r0 + r;
    if (row >= N) return;
    float v = hh[(size_t)row*DD + j];
    h[(size_t)row*DD + j] = fmaxf(v*sc + sh, 0.f);
  }
}

// ---------------- zero helper ----------------
__global__ __launch_bounds__(256) void zero_kernel(float* __restrict__ p, int n) {
  for (int i = blockIdx.x*256 + threadIdx.x; i < n; i += gridDim.x*256) p[i] = 0.f;
}

// ---------------- mean pool by (sorted) batch ----------------
__global__ __launch_bounds__(256) void pool_kernel(
    const float* __restrict__ h, const int* __restrict__ batch,
    float* __restrict__ hgsum, int* __restrict__ hgcnt, int N)
{
  int j = threadIdx.x;
  int r0 = blockIdx.x * 64;
  int cur = -1; float acc = 0.f; int run = 0;
  for (int r = 0; r < 64; ++r) {
    int row = r0 + r;
    if (row >= N) break;
    int g = batch[row];
    if (g != cur) {
      if (cur >= 0) {
        atomicAdd(&hgsum[(size_t)cur*DD + j], acc);
        if (j == 0) atomicAdd(&hgcnt[cur], run);
      }
      cur = g; acc = 0.f; run = 0;
    }
    acc += h[(size_t)row*DD + j];
    run++;
  }
  if (cur >= 0) {
    atomicAdd(&hgsum[(size_t)cur*DD + j], acc);
    if (j == 0) atomicAdd(&hgcnt[cur], run);
  }
}

__global__ __launch_bounds__(256) void hgfin_kernel(
    const float* __restrict__ hgsum, const int* __restrict__ hgcnt, float* __restrict__ hg)
{
  int g = blockIdx.x, j = threadIdx.x;
  float c = (float)max(hgcnt[g], 1);
  hg[(size_t)g*DD + j] = hgsum[(size_t)g*DD + j] / c;
}

// ---------------- projection head: small GEMM + col stats ----------------
__global__ __launch_bounds__(256) void proj_gemm_kernel(
    const float* __restrict__ in, const float* __restrict__ W,
    float* __restrict__ outb, float* __restrict__ pstat)
{
  __shared__ float sA[16][17];
  __shared__ float sB[16][17];
  int tx = threadIdx.x, ty = threadIdx.y;
  int r = blockIdx.y*16 + ty;
  int c = blockIdx.x*16 + tx;
  float acc = 0.f;
  for (int k0 = 0; k0 < DD; k0 += 16) {
    sA[ty][tx] = in[(size_t)r*DD + k0 + tx];
    sB[ty][tx] = W[(size_t)(blockIdx.x*16 + ty)*DD + k0 + tx];
    __syncthreads();
#pragma unroll
    for (int kk = 0; kk < 16; ++kk) acc += sA[ty][kk] * sB[tx][kk];
    __syncthreads();
  }
  outb[(size_t)r*DD + c] = acc;
  sA[ty][tx] = acc; sB[ty][tx] = acc*acc;
  __syncthreads();
  for (int o = 8; o > 0; o >>= 1) {
    if (ty < o) { sA[ty][tx] += sA[ty+o][tx]; sB[ty][tx] += sB[ty+o][tx]; }
    __syncthreads();
  }
  if (ty == 0) { atomicAdd(&pstat[c], sA[0][tx]); atomicAdd(&pstat[DD + c], sB[0][tx]); }
}

__global__ __launch_bounds__(256) void proj_bn_kernel(
    const float* __restrict__ tin, const float* __restrict__ pstat,
    const float* __restrict__ g, const float* __restrict__ b,
    float* __restrict__ outp, int do_relu)
{
  int c = threadIdx.x, r = blockIdx.x;
  float m = pstat[c] * (1.0f/NGRAPH);
  float var = fmaxf(pstat[DD + c] * (1.0f/NGRAPH) - m*m, 0.f);
  float sc = g[c] * rsqrtf(var + BNEPS);
  float sh = b[c] - m*sc;
  float v = tin[(size_t)r*DD + c]*sc + sh;
  outp[(size_t)r*DD + c] = do_relu ? fmaxf(v, 0.f) : v;
}

// ---------------- output MLP ----------------
__global__ __launch_bounds__(128) void out_kernel(
    const float* __restrict__ hgf, const float* __restrict__ ow1,
    const float* __restrict__ ob1, const float* __restrict__ ow2,
    const float* __restrict__ ob2, float* __restrict__ outp)
{
  __shared__ float rowv[DD];
  __shared__ float z[128];
  int r = blockIdx.x, t = threadIdx.x;
  rowv[t] = hgf[(size_t)r*DD + t];
  rowv[t + 128] = hgf[(size_t)r*DD + t + 128];
  __syncthreads();
  float a = ob1[t];
  for (int k = 0; k < DD; ++k) a += rowv[k] * ow1[(size_t)t*DD + k];
  z[t] = fmaxf(a, 0.f) + log1pf(expf(-fabsf(a)));   // softplus, stable
  __syncthreads();
  if (t < 2) {
    float o = ob2[t];
    for (int k = 0; k < 128; ++k) o += z[k] * ow2[t*128 + k];
    outp[r*2 + t] = o;
  }
}

// ---------------- host launcher ----------------
extern "C" void kernel_launch(void* const* d_in, const int* in_sizes, int n_in,
                              void* d_out, int out_size, void* d_ws, size_t ws_size,
                              hipStream_t stream)
{
  const int* x_feats = (const int*)d_in[0];
  const int* ei      = (const int*)d_in[1];
  const int* ea      = (const int*)d_in[2];
  const int* batch   = (const int*)d_in[3];
  const float* nt1 = (const float*)d_in[4];
  const float* nt2 = (const float*)d_in[5];
  const float* nt3 = (const float*)d_in[6];
  const float* nt4 = (const float*)d_in[7];
  const float* nt5 = (const float*)d_in[8];
  const float* nt6 = (const float*)d_in[9];
  const float* et1 = (const float*)d_in[10];
  const float* et2 = (const float*)d_in[11];
  const float* et3 = (const float*)d_in[12];
  const float* et4 = (const float*)d_in[13];
  const float* et5 = (const float*)d_in[14];
  const float* w1  = (const float*)d_in[15];
  const float* b1  = (const float*)d_in[16];
  const float* w2  = (const float*)d_in[17];
  const float* b2  = (const float*)d_in[18];
  const float* bng = (const float*)d_in[19];
  const float* bnb = (const float*)d_in[20];
  const float* pw  = (const float*)d_in[21];
  const float* pg  = (const float*)d_in[22];
  const float* pb  = (const float*)d_in[23];
  const float* ow1 = (const float*)d_in[24];
  const float* ob1 = (const float*)d_in[25];
  const float* ow2 = (const float*)d_in[26];
  const float* ob2 = (const float*)d_in[27];

  const int N = in_sizes[0] / 6;       // 20000
  const int E = in_sizes[1] / 2;       // 320000
  const int Mp = ((N + 127) >> 7) << 7; // 20096

  unsigned char* wp = (unsigned char*)d_ws;
  size_t off = 0;
  auto carve = [&](size_t bytes) -> void* {
    void* p = wp + off;
    off += (bytes + 255) & ~(size_t)255;
    return p;
  };

  // aggrh (fp16, 10.3MB) and hh (f32, 20.6MB) share one region: disjoint lifetimes.
  void* shared_reg   = carve((size_t)Mp * DD * 4);
  _Float16* aggrh    = (_Float16*)shared_reg;
  float* hh          = (float*)shared_reg;
  _Float16* hidh     = (_Float16*)carve((size_t)Mp * TWO_D * 2);
  float* h           = (float*)carve((size_t)N * DD * 4);
  _Float16* w1h      = (_Float16*)carve((size_t)NLAYER * TWO_D * DD * 2);
  _Float16* w2h      = (_Float16*)carve((size_t)NLAYER * TWO_D * DD * 2);
  float* etabg       = (float*)carve((size_t)NLAYER * 33 * DD * 4);
  float* stats       = (float*)carve(2 * DD * 4);
  int* deg           = (int*)carve((size_t)N * 4);
  int* row_start     = (int*)carve((size_t)(N + 1) * 4);
  int* cursor        = (int*)carve((size_t)N * 4);
  int* packed        = (int*)carve((size_t)E * 4);
  int* esort         = (int*)carve((size_t)E * 4);
  // contiguous zero range: hgsum + hgcnt + pstats
  float* hgsum       = (float*)carve((size_t)NGRAPH * DD * 4);
  int* hgcnt         = (int*)carve((size_t)NGRAPH * 4);
  float* pstats      = (float*)carve(3 * 2 * DD * 4);
  float* hgA         = (float*)carve((size_t)NGRAPH * DD * 4);
  float* hgB         = (float*)carve((size_t)NGRAPH * DD * 4);
  float* t0          = (float*)carve((size_t)NGRAPH * DD * 4);
  (void)ws_size; (void)n_in; (void)out_size;

  const int EB = (E + 255) / 256;

  embed_kernel<<<N, 256, 0, stream>>>(x_feats, nt1, nt2, nt3, nt4, nt5, nt6, h, deg, N);
  hist_pack_kernel<<<EB, 256, 0, stream>>>(ei, ea, deg, packed, E);
  scan_kernel<<<1, 1024, 0, stream>>>(deg, row_start, cursor, N);
  scatter_kernel<<<EB, 256, 0, stream>>>(ei, packed, cursor, esort, E);
  wconv_kernel<<<1024, 256, 0, stream>>>(w1, w2, w1h, w2h, NLAYER * TWO_D * DD);
  etab_kernel<<<NLAYER * 33, 256, 0, stream>>>(et1, et2, et3, et4, et5, etabg);
  // zero hgsum/hgcnt/pstats (contiguous, 256-aligned sizes; 192 extra floats of slack)
  zero_kernel<<<128, 256, 0, stream>>>(hgsum, NGRAPH*DD + NGRAPH + 3*2*DD + 192);

  const int gm = Mp >> 7;
  for (int l = 0; l < NLAYER; ++l) {
    aggr_kernel<<<640, 256, 0, stream>>>(h, etabg + (size_t)l*33*DD, row_start, esort,
                                         aggrh, stats, N);
    gemm_bt<0><<<gm * (TWO_D >> 7), 256, 0, stream>>>(
        aggrh, w1h + (size_t)l*TWO_D*DD, b1 + l*TWO_D, (void*)hidh, nullptr,
        DD, TWO_D, N);
    gemm_bt<1><<<gm * (DD >> 7), 256, 0, stream>>>(
        hidh, w2h + (size_t)l*DD*TWO_D, b2 + l*DD, (void*)hh, stats,
        TWO_D, DD, N);
    bn_relu_kernel<<<(N + 63) / 64, 256, 0, stream>>>(
        hh, stats, bng + l*DD, bnb + l*DD, h, N);
  }

  pool_kernel<<<(N + 63) / 64, 256, 0, stream>>>(h, batch, hgsum, hgcnt, N);
  hgfin_kernel<<<NGRAPH, 256, 0, stream>>>(hgsum, hgcnt, hgA);

  dim3 pgrid(16, 16), pblk(16, 16);
  proj_gemm_kernel<<<pgrid, pblk, 0, stream>>>(hgA, pw + 0*DD*DD, t0, pstats + 0*2*DD);
  proj_bn_kernel<<<NGRAPH, 256, 0, stream>>>(t0, pstats + 0*2*DD, pg + 0*DD, pb + 0*DD, hgB, 1);
  proj_gemm_kernel<<<pgrid, pblk, 0, stream>>>(hgB, pw + 1*DD*DD, t0, pstats + 1*2*DD);
  proj_bn_kernel<<<NGRAPH, 256, 0, stream>>>(t0, pstats + 1*2*DD, pg + 1*DD, pb + 1*DD, hgA, 1);
  proj_gemm_kernel<<<pgrid, pblk, 0, stream>>>(hgA, pw + 2*DD*DD, t0, pstats + 2*2*DD);
  proj_bn_kernel<<<NGRAPH, 256, 0, stream>>>(t0, pstats + 2*2*DD, pg + 2*DD, pb + 2*DD, hgB, 0);

  out_kernel<<<NGRAPH, 128, 0, stream>>>(hgB, ow1, ob1, ow2, ob2, (float*)d_out);
}

// Round 3
// 596.959 us; speedup vs baseline: 1.2963x; 1.2963x over previous
//
#include <hip/hip_runtime.h>

#define DD 256
#define TWO_D 512
#define NLAYER 5
#define NGRAPH 256
#define BNEPS 1e-5f

typedef __attribute__((ext_vector_type(8))) _Float16 half8;
typedef __attribute__((ext_vector_type(4))) _Float16 half4;
typedef __attribute__((ext_vector_type(4))) float f32x4;
typedef __attribute__((address_space(1))) void gvoid_t;
typedef __attribute__((address_space(3))) void svoid_t;

// ---------------- embedding (fp16 h) + zero deg ----------------
__global__ __launch_bounds__(256) void embed_kernel(
    const int* __restrict__ xf,
    const float* __restrict__ nt1, const float* __restrict__ nt2,
    const float* __restrict__ nt3, const float* __restrict__ nt4,
    const float* __restrict__ nt5, const float* __restrict__ nt6,
    _Float16* __restrict__ h16, int* __restrict__ deg, int N)
{
  int i = blockIdx.x;
  int j = threadIdx.x;
  if (i >= N) return;
  if (j == 0) deg[i] = 0;
  int x0 = xf[i*6+0], x1 = xf[i*6+1], x2 = xf[i*6+2];
  int x3 = xf[i*6+3], x4 = xf[i*6+4], x5 = xf[i*6+5];
  float v = nt1[x0*DD+j] + nt2[x1*DD+j] + nt3[x2*DD+j]
          + nt4[x3*DD+j] + nt5[x4*DD+j] + nt6[x5*DD+j];
  h16[(size_t)i*DD + j] = (_Float16)v;
}

// ---------------- CSR build ----------------
__global__ __launch_bounds__(256) void hist_pack_kernel(
    const int* __restrict__ ei, const int* __restrict__ ea,
    int* __restrict__ deg, int* __restrict__ packed, int E)
{
  int e = blockIdx.x*256 + threadIdx.x;
  if (e >= E) return;
  int src = ei[e];
  int dst = ei[E + e];
  int code = (ea[e*5+0]&1) | ((ea[e*5+1]&1)<<1) | ((ea[e*5+2]&1)<<2)
           | ((ea[e*5+3]&1)<<3) | ((ea[e*5+4]&1)<<4);
  packed[e] = src | (code << 16);
  atomicAdd(&deg[dst], 1);
}

__global__ __launch_bounds__(1024) void scan_kernel(
    const int* __restrict__ deg, int* __restrict__ row_start,
    int* __restrict__ cursor, int N)
{
  __shared__ int sh[1024];
  __shared__ int carry_s;
  int t = threadIdx.x;
  if (t == 0) carry_s = 0;
  __syncthreads();
  for (int base = 0; base < N; base += 1024) {
    int carry = carry_s;
    int idx = base + t;
    int v = (idx < N) ? deg[idx] : 0;
    sh[t] = v;
    __syncthreads();
    for (int off = 1; off < 1024; off <<= 1) {
      int x = (t >= off) ? sh[t - off] : 0;
      __syncthreads();
      sh[t] += x;
      __syncthreads();
    }
    int incl = sh[t];
    if (idx < N) { int ex = carry + incl - v; row_start[idx] = ex; cursor[idx] = ex; }
    __syncthreads();
    if (t == 1023) carry_s = carry + sh[1023];
    __syncthreads();
  }
  if (t == 0) row_start[N] = carry_s;
}

__global__ __launch_bounds__(256) void scatter_kernel(
    const int* __restrict__ ei, const int* __restrict__ packed,
    int* __restrict__ cursor, int* __restrict__ esort, int E)
{
  int e = blockIdx.x*256 + threadIdx.x;
  if (e >= E) return;
  int dst = ei[E + e];
  int pos = atomicAdd(&cursor[dst], 1);
  esort[pos] = packed[e];
}

// ---------------- weight fp16 + fp16 edge-table precompute ----------------
__global__ __launch_bounds__(256) void wconv_kernel(
    const float* __restrict__ w1, const float* __restrict__ w2,
    _Float16* __restrict__ w1h, _Float16* __restrict__ w2h, int n)
{
  for (int i = blockIdx.x*256 + threadIdx.x; i < n; i += gridDim.x*256) {
    w1h[i] = (_Float16)w1[i];
    w2h[i] = (_Float16)w2[i];
  }
}

__global__ __launch_bounds__(256) void etab_kernel(
    const float* __restrict__ et1, const float* __restrict__ et2,
    const float* __restrict__ et3, const float* __restrict__ et4,
    const float* __restrict__ et5, _Float16* __restrict__ etab)
{
  int b = blockIdx.x;
  int l = b / 33, c = b % 33;
  int j = threadIdx.x;
  int a0 = (c==32)?4:(c&1);
  int a1 = (c==32)?0:((c>>1)&1);
  int a2 = (c==32)?0:((c>>2)&1);
  int a3 = (c==32)?0:((c>>3)&1);
  int a4 = (c==32)?0:((c>>4)&1);
  etab[((size_t)l*33 + c)*DD + j] = (_Float16)(
      et1[(l*5+a0)*DD+j] + et2[(l*4+a1)*DD+j] + et3[(l*2+a2)*DD+j]
    + et4[(l*2+a3)*DD+j] + et5[(l*2+a4)*DD+j]);
}

// ---------------- BN prep: stats -> per-column scale/shift, then zero stats ----------------
__global__ __launch_bounds__(256) void bn_prep_kernel(
    float* __restrict__ stats, const float* __restrict__ g, const float* __restrict__ b,
    float* __restrict__ scsh, float inv_n)
{
  int j = threadIdx.x;
  float m = stats[j] * inv_n;
  float var = fmaxf(stats[DD + j] * inv_n - m*m, 0.f);
  float sc = g[j] * rsqrtf(var + BNEPS);
  scsh[j] = sc;
  scsh[DD + j] = b[j] - m*sc;
  stats[j] = 0.f; stats[DD + j] = 0.f;
}

// ---------------- aggregation: one wave per node, fused BN+ReLU on gathered rows ----------------
// APPLY_BN=0: hsrc is already the layer input (embedding). APPLY_BN=1: hsrc is raw
// pre-BN hh16; apply relu(h*sc+sh) per element using scsh.
template<int APPLY_BN>
__global__ __launch_bounds__(256) void aggr_kernel(
    const _Float16* __restrict__ hsrc, const _Float16* __restrict__ etab_l,
    const int* __restrict__ row_start, const int* __restrict__ esort,
    const float* __restrict__ scsh,
    _Float16* __restrict__ aggrh, int N)
{
  __shared__ __attribute__((aligned(16))) _Float16 se[33*DD];
  for (int i = threadIdx.x; i < 33*DD/8; i += 256)
    ((int4*)se)[i] = ((const int4*)etab_l)[i];
  __syncthreads();
  const int wave = threadIdx.x >> 6, lane = threadIdx.x & 63;
  const int c4 = lane << 2;
  float sc0 = 1.f, sc1 = 1.f, sc2 = 1.f, sc3 = 1.f;
  float sh0 = 0.f, sh1 = 0.f, sh2 = 0.f, sh3 = 0.f;
  if (APPLY_BN) {
    sc0 = scsh[c4+0]; sc1 = scsh[c4+1]; sc2 = scsh[c4+2]; sc3 = scsh[c4+3];
    sh0 = scsh[DD+c4+0]; sh1 = scsh[DD+c4+1]; sh2 = scsh[DD+c4+2]; sh3 = scsh[DD+c4+3];
  }
  const int W0 = blockIdx.x*4 + wave, NW = gridDim.x*4;

#define BNX(h4, out0, out1, out2, out3)                                   \
  { float t0_ = (float)(h4).x, t1_ = (float)(h4).y,                       \
          t2_ = (float)(h4).z, t3_ = (float)(h4).w;                       \
    if (APPLY_BN) {                                                       \
      t0_ = fmaxf(t0_*sc0 + sh0, 0.f); t1_ = fmaxf(t1_*sc1 + sh1, 0.f);  \
      t2_ = fmaxf(t2_*sc2 + sh2, 0.f); t3_ = fmaxf(t3_*sc3 + sh3, 0.f);  \
    }                                                                     \
    out0 = t0_; out1 = t1_; out2 = t2_; out3 = t3_; }

  for (int node = W0; node < N; node += NW) {
    int p  = row_start[node];
    int pe = row_start[node+1];
    const half4 hv = *(const half4*)(hsrc + (size_t)node*DD + c4);
    const half4 sv = *(const half4*)(se + 32*DD + c4);
    float ax, ay, az, aw;
    BNX(hv, ax, ay, az, aw);
    ax += (float)sv.x; ay += (float)sv.y; az += (float)sv.z; aw += (float)sv.w;
    for (; p + 4 <= pe; p += 4) {
      int pk0 = esort[p], pk1 = esort[p+1], pk2 = esort[p+2], pk3 = esort[p+3];
      const half4 h0 = *(const half4*)(hsrc + (size_t)(pk0 & 0xffff)*DD + c4);
      const half4 h1 = *(const half4*)(hsrc + (size_t)(pk1 & 0xffff)*DD + c4);
      const half4 h2 = *(const half4*)(hsrc + (size_t)(pk2 & 0xffff)*DD + c4);
      const half4 h3 = *(const half4*)(hsrc + (size_t)(pk3 & 0xffff)*DD + c4);
      const half4 e0 = *(const half4*)(se + (pk0 >> 16)*DD + c4);
      const half4 e1 = *(const half4*)(se + (pk1 >> 16)*DD + c4);
      const half4 e2 = *(const half4*)(se + (pk2 >> 16)*DD + c4);
      const half4 e3 = *(const half4*)(se + (pk3 >> 16)*DD + c4);
      float b0x,b0y,b0z,b0w, b1x,b1y,b1z,b1w, b2x,b2y,b2z,b2w, b3x,b3y,b3z,b3w;
      BNX(h0, b0x,b0y,b0z,b0w); BNX(h1, b1x,b1y,b1z,b1w);
      BNX(h2, b2x,b2y,b2z,b2w); BNX(h3, b3x,b3y,b3z,b3w);
      ax += (b0x+(float)e0.x) + (b1x+(float)e1.x) + (b2x+(float)e2.x) + (b3x+(float)e3.x);
      ay += (b0y+(float)e0.y) + (b1y+(float)e1.y) + (b2y+(float)e2.y) + (b3y+(float)e3.y);
      az += (b0z+(float)e0.z) + (b1z+(float)e1.z) + (b2z+(float)e2.z) + (b3z+(float)e3.z);
      aw += (b0w+(float)e0.w) + (b1w+(float)e1.w) + (b2w+(float)e2.w) + (b3w+(float)e3.w);
    }
    for (; p < pe; ++p) {
      int pk = esort[p];
      const half4 hx = *(const half4*)(hsrc + (size_t)(pk & 0xffff)*DD + c4);
      const half4 ex = *(const half4*)(se + (pk >> 16)*DD + c4);
      float bx, by, bz, bw;
      BNX(hx, bx, by, bz, bw);
      ax += bx + (float)ex.x; ay += by + (float)ex.y;
      az += bz + (float)ex.z; aw += bw + (float)ex.w;
    }
    half4 o;
    o.x = (_Float16)ax; o.y = (_Float16)ay; o.z = (_Float16)az; o.w = (_Float16)aw;
    *(half4*)(aggrh + (size_t)node*DD + c4) = o;
  }
#undef BNX
}

// ---------------- fp16 MFMA GEMM: C[M,Nw] = A[M,K] * B[Nw,K]^T + bias ----------------
// RELU=1: fp16 out with relu (hidden layer).  STATS=1: fp16 out, no relu, column
// stats over rows < Nreal (pre-BN output).
template<int RELU, int STATS>
__global__ __launch_bounds__(256) void gemm_bt(
    const _Float16* __restrict__ A,
    const _Float16* __restrict__ B,
    const float* __restrict__ bias,
    _Float16* __restrict__ O,
    float* __restrict__ stats,
    int K, int Nw, int Nreal)
{
  __shared__ __attribute__((aligned(16))) _Float16 lA[128*32];
  __shared__ __attribute__((aligned(16))) _Float16 lB[128*32];
  const int NT = Nw >> 7;
  const int bm = blockIdx.x / NT, bn = blockIdx.x % NT;
  const int m0 = bm << 7, n0 = bn << 7;
  const int t = threadIdx.x;
  const int wave = t >> 6, lane = t & 63;
  const int wm = wave & 1, wn = wave >> 1;
  const int r15 = lane & 15, quad = lane >> 4;
  const int srow = lane >> 2, sq = (lane & 3) << 3;
  f32x4 acc[4][4] = {};
  for (int k0 = 0; k0 < K; k0 += 32) {
    __syncthreads();
#pragma unroll
    for (int i = 0; i < 2; ++i) {
      const int seg = wave*2 + i;
      const int row = seg*16 + srow;
      __builtin_amdgcn_global_load_lds((gvoid_t*)(A + (size_t)(m0+row)*K + k0 + sq),
                                       (svoid_t*)(lA + seg*512), 16, 0, 0);
      __builtin_amdgcn_global_load_lds((gvoid_t*)(B + (size_t)(n0+row)*K + k0 + sq),
                                       (svoid_t*)(lB + seg*512), 16, 0, 0);
    }
    __syncthreads();
    half8 af[4], bfr[4];
#pragma unroll
    for (int f = 0; f < 4; ++f) {
      af[f]  = *(const half8*)(lA + (((wm<<6) + (f<<4) + r15) << 5) + (quad<<3));
      bfr[f] = *(const half8*)(lB + (((wn<<6) + (f<<4) + r15) << 5) + (quad<<3));
    }
#pragma unroll
    for (int fm = 0; fm < 4; ++fm)
#pragma unroll
      for (int fn = 0; fn < 4; ++fn)
        acc[fm][fn] = __builtin_amdgcn_mfma_f32_16x16x32_f16(af[fm], bfr[fn], acc[fm][fn], 0, 0, 0);
  }
#pragma unroll
  for (int fn = 0; fn < 4; ++fn) {
    const int col = n0 + (wn<<6) + (fn<<4) + r15;
    const float bv = bias[col];
    float s1 = 0.f, s2 = 0.f;
#pragma unroll
    for (int fm = 0; fm < 4; ++fm) {
      const int rowb = m0 + (wm<<6) + (fm<<4) + (quad<<2);
#pragma unroll
      for (int r = 0; r < 4; ++r) {
        float v = acc[fm][fn][r] + bv;
        if (RELU) v = fmaxf(v, 0.f);
        O[(size_t)(rowb + r)*Nw + col] = (_Float16)v;
        if (STATS && (rowb + r < Nreal)) { s1 += v; s2 += v*v; }
      }
    }
    if (STATS) {
      s1 += __shfl_xor(s1, 16); s1 += __shfl_xor(s1, 32);
      s2 += __shfl_xor(s2, 16); s2 += __shfl_xor(s2, 32);
      if (lane < 16) { atomicAdd(&stats[col], s1); atomicAdd(&stats[DD + col], s2); }
    }
  }
}

// ---------------- zero helper ----------------
__global__ __launch_bounds__(256) void zero_kernel(float* __restrict__ p, int n) {
  for (int i = blockIdx.x*256 + threadIdx.x; i < n; i += gridDim.x*256) p[i] = 0.f;
}

// ---------------- mean pool by (sorted) batch, fused BN+ReLU ----------------
__global__ __launch_bounds__(256) void pool_kernel(
    const _Float16* __restrict__ hh16, const float* __restrict__ scsh,
    const int* __restrict__ batch,
    float* __restrict__ hgsum, int* __restrict__ hgcnt, int N)
{
  int j = threadIdx.x;
  float sc = scsh[j], sh = scsh[DD + j];
  int r0 = blockIdx.x * 64;
  int cur = -1; float acc = 0.f; int run = 0;
  for (int r = 0; r < 64; ++r) {
    int row = r0 + r;
    if (row >= N) break;
    int g = batch[row];
    if (g != cur) {
      if (cur >= 0) {
        atomicAdd(&hgsum[(size_t)cur*DD + j], acc);
        if (j == 0) atomicAdd(&hgcnt[cur], run);
      }
      cur = g; acc = 0.f; run = 0;
    }
    float v = (float)hh16[(size_t)row*DD + j];
    acc += fmaxf(v*sc + sh, 0.f);
    run++;
  }
  if (cur >= 0) {
    atomicAdd(&hgsum[(size_t)cur*DD + j], acc);
    if (j == 0) atomicAdd(&hgcnt[cur], run);
  }
}

__global__ __launch_bounds__(256) void hgfin_kernel(
    const float* __restrict__ hgsum, const int* __restrict__ hgcnt, float* __restrict__ hg)
{
  int g = blockIdx.x, j = threadIdx.x;
  float c = (float)max(hgcnt[g], 1);
  hg[(size_t)g*DD + j] = hgsum[(size_t)g*DD + j] / c;
}

// ---------------- projection head: small GEMM + col stats ----------------
__global__ __launch_bounds__(256) void proj_gemm_kernel(
    const float* __restrict__ in, const float* __restrict__ W,
    float* __restrict__ outb, float* __restrict__ pstat)
{
  __shared__ float sA[16][17];
  __shared__ float sB[16][17];
  int tx = threadIdx.x, ty = threadIdx.y;
  int r = blockIdx.y*16 + ty;
  int c = blockIdx.x*16 + tx;
  float acc = 0.f;
  for (int k0 = 0; k0 < DD; k0 += 16) {
    sA[ty][tx] = in[(size_t)r*DD + k0 + tx];
    sB[ty][tx] = W[(size_t)(blockIdx.x*16 + ty)*DD + k0 + tx];
    __syncthreads();
#pragma unroll
    for (int kk = 0; kk < 16; ++kk) acc += sA[ty][kk] * sB[tx][kk];
    __syncthreads();
  }
  outb[(size_t)r*DD + c] = acc;
  sA[ty][tx] = acc; sB[ty][tx] = acc*acc;
  __syncthreads();
  for (int o = 8; o > 0; o >>= 1) {
    if (ty < o) { sA[ty][tx] += sA[ty+o][tx]; sB[ty][tx] += sB[ty+o][tx]; }
    __syncthreads();
  }
  if (ty == 0) { atomicAdd(&pstat[c], sA[0][tx]); atomicAdd(&pstat[DD + c], sB[0][tx]); }
}

__global__ __launch_bounds__(256) void proj_bn_kernel(
    const float* __restrict__ tin, const float* __restrict__ pstat,
    const float* __restrict__ g, const float* __restrict__ b,
    float* __restrict__ outp, int do_relu)
{
  int c = threadIdx.x, r = blockIdx.x;
  float m = pstat[c] * (1.0f/NGRAPH);
  float var = fmaxf(pstat[DD + c] * (1.0f/NGRAPH) - m*m, 0.f);
  float sc = g[c] * rsqrtf(var + BNEPS);
  float sh = b[c] - m*sc;
  float v = tin[(size_t)r*DD + c]*sc + sh;
  outp[(size_t)r*DD + c] = do_relu ? fmaxf(v, 0.f) : v;
}

// ---------------- output MLP ----------------
__global__ __launch_bounds__(128) void out_kernel(
    const float* __restrict__ hgf, const float* __restrict__ ow1,
    const float* __restrict__ ob1, const float* __restrict__ ow2,
    const float* __restrict__ ob2, float* __restrict__ outp)
{
  __shared__ float rowv[DD];
  __shared__ float z[128];
  int r = blockIdx.x, t = threadIdx.x;
  rowv[t] = hgf[(size_t)r*DD + t];
  rowv[t + 128] = hgf[(size_t)r*DD + t + 128];
  __syncthreads();
  float a = ob1[t];
  for (int k = 0; k < DD; ++k) a += rowv[k] * ow1[(size_t)t*DD + k];
  z[t] = fmaxf(a, 0.f) + log1pf(expf(-fabsf(a)));   // softplus, stable
  __syncthreads();
  if (t < 2) {
    float o = ob2[t];
    for (int k = 0; k < 128; ++k) o += z[k] * ow2[t*128 + k];
    outp[r*2 + t] = o;
  }
}

// ---------------- host launcher ----------------
extern "C" void kernel_launch(void* const* d_in, const int* in_sizes, int n_in,
                              void* d_out, int out_size, void* d_ws, size_t ws_size,
                              hipStream_t stream)
{
  const int* x_feats = (const int*)d_in[0];
  const int* ei      = (const int*)d_in[1];
  const int* ea      = (const int*)d_in[2];
  const int* batch   = (const int*)d_in[3];
  const float* nt1 = (const float*)d_in[4];
  const float* nt2 = (const float*)d_in[5];
  const float* nt3 = (const float*)d_in[6];
  const float* nt4 = (const float*)d_in[7];
  const float* nt5 = (const float*)d_in[8];
  const float* nt6 = (const float*)d_in[9];
  const float* et1 = (const float*)d_in[10];
  const float* et2 = (const float*)d_in[11];
  const float* et3 = (const float*)d_in[12];
  const float* et4 = (const float*)d_in[13];
  const float* et5 = (const float*)d_in[14];
  const float* w1  = (const float*)d_in[15];
  const float* b1  = (const float*)d_in[16];
  const float* w2  = (const float*)d_in[17];
  const float* b2  = (const float*)d_in[18];
  const float* bng = (const float*)d_in[19];
  const float* bnb = (const float*)d_in[20];
  const float* pw  = (const float*)d_in[21];
  const float* pg  = (const float*)d_in[22];
  const float* pb  = (const float*)d_in[23];
  const float* ow1 = (const float*)d_in[24];
  const float* ob1 = (const float*)d_in[25];
  const float* ow2 = (const float*)d_in[26];
  const float* ob2 = (const float*)d_in[27];

  const int N = in_sizes[0] / 6;        // 20000
  const int E = in_sizes[1] / 2;        // 320000
  const int Mp = ((N + 127) >> 7) << 7; // 20096

  unsigned char* wp = (unsigned char*)d_ws;
  size_t off = 0;
  auto carve = [&](size_t bytes) -> void* {
    void* p = wp + off;
    off += (bytes + 255) & ~(size_t)255;
    return p;
  };

  _Float16* h16      = (_Float16*)carve((size_t)N * DD * 2);       // embedding (layer-0 input)
  _Float16* aggrh    = (_Float16*)carve((size_t)Mp * DD * 2);      // aggregation out / gemm1 in
  _Float16* hh16     = (_Float16*)carve((size_t)Mp * DD * 2);      // gemm2 out (pre-BN)
  _Float16* hidh     = (_Float16*)carve((size_t)Mp * TWO_D * 2);   // gemm1 out / gemm2 in
  _Float16* w1h      = (_Float16*)carve((size_t)NLAYER * TWO_D * DD * 2);
  _Float16* w2h      = (_Float16*)carve((size_t)NLAYER * TWO_D * DD * 2);
  _Float16* etabg    = (_Float16*)carve((size_t)NLAYER * 33 * DD * 2);
  float* scsh        = (float*)carve(2 * DD * 4);
  int* deg           = (int*)carve((size_t)N * 4);
  int* row_start     = (int*)carve((size_t)(N + 1) * 4);
  int* cursor        = (int*)carve((size_t)N * 4);
  int* packed        = (int*)carve((size_t)E * 4);
  int* esort         = (int*)carve((size_t)E * 4);
  // contiguous zero range: stats + hgsum + hgcnt + pstats (all 256B-multiple carves)
  float* stats       = (float*)carve(2 * DD * 4);
  float* hgsum       = (float*)carve((size_t)NGRAPH * DD * 4);
  int* hgcnt         = (int*)carve((size_t)NGRAPH * 4);
  float* pstats      = (float*)carve(3 * 2 * DD * 4);
  float* hgA         = (float*)carve((size_t)NGRAPH * DD * 4);
  float* hgB         = (float*)carve((size_t)NGRAPH * DD * 4);
  float* t0          = (float*)carve((size_t)NGRAPH * DD * 4);
  (void)ws_size; (void)n_in; (void)out_size;

  const int EB = (E + 255) / 256;
  const float inv_n = 1.0f / (float)N;

  embed_kernel<<<N, 256, 0, stream>>>(x_feats, nt1, nt2, nt3, nt4, nt5, nt6, h16, deg, N);
  hist_pack_kernel<<<EB, 256, 0, stream>>>(ei, ea, deg, packed, E);
  scan_kernel<<<1, 1024, 0, stream>>>(deg, row_start, cursor, N);
  scatter_kernel<<<EB, 256, 0, stream>>>(ei, packed, cursor, esort, E);
  wconv_kernel<<<1024, 256, 0, stream>>>(w1, w2, w1h, w2h, NLAYER * TWO_D * DD);
  etab_kernel<<<NLAYER * 33, 256, 0, stream>>>(et1, et2, et3, et4, et5, etabg);
  // zero stats + hgsum + hgcnt + pstats (contiguous)
  zero_kernel<<<128, 256, 0, stream>>>(stats, 2*DD + NGRAPH*DD + NGRAPH + 3*2*DD);

  const int gm = Mp >> 7;
  for (int l = 0; l < NLAYER; ++l) {
    if (l == 0) {
      aggr_kernel<0><<<2048, 256, 0, stream>>>(h16, etabg, row_start, esort,
                                               nullptr, aggrh, N);
    } else {
      bn_prep_kernel<<<1, 256, 0, stream>>>(stats, bng + (l-1)*DD, bnb + (l-1)*DD,
                                            scsh, inv_n);
      aggr_kernel<1><<<2048, 256, 0, stream>>>(hh16, etabg + (size_t)l*33*DD,
                                               row_start, esort, scsh, aggrh, N);
    }
    gemm_bt<1,0><<<gm * (TWO_D >> 7), 256, 0, stream>>>(
        aggrh, w1h + (size_t)l*TWO_D*DD, b1 + l*TWO_D, hidh, nullptr,
        DD, TWO_D, N);
    gemm_bt<0,1><<<gm * (DD >> 7), 256, 0, stream>>>(
        hidh, w2h + (size_t)l*DD*TWO_D, b2 + l*DD, hh16, stats,
        TWO_D, DD, N);
  }
  // final layer BN folded into pool
  bn_prep_kernel<<<1, 256, 0, stream>>>(stats, bng + (NLAYER-1)*DD, bnb + (NLAYER-1)*DD,
                                        scsh, inv_n);
  pool_kernel<<<(N + 63) / 64, 256, 0, stream>>>(hh16, scsh, batch, hgsum, hgcnt, N);
  hgfin_kernel<<<NGRAPH, 256, 0, stream>>>(hgsum, hgcnt, hgA);

  dim3 pgrid(16, 16), pblk(16, 16);
  proj_gemm_kernel<<<pgrid, pblk, 0, stream>>>(hgA, pw + 0*DD*DD, t0, pstats + 0*2*DD);
  proj_bn_kernel<<<NGRAPH, 256, 0, stream>>>(t0, pstats + 0*2*DD, pg + 0*DD, pb + 0*DD, hgB, 1);
  proj_gemm_kernel<<<pgrid, pblk, 0, stream>>>(hgB, pw + 1*DD*DD, t0, pstats + 1*2*DD);
  proj_bn_kernel<<<NGRAPH, 256, 0, stream>>>(t0, pstats + 1*2*DD, pg + 1*DD, pb + 1*DD, hgA, 1);
  proj_gemm_kernel<<<pgrid, pblk, 0, stream>>>(hgA, pw + 2*DD*DD, t0, pstats + 2*2*DD);
  proj_bn_kernel<<<NGRAPH, 256, 0, stream>>>(t0, pstats + 2*2*DD, pg + 2*DD, pb + 2*DD, hgB, 0);

  out_kernel<<<NGRAPH, 128, 0, stream>>>(hgB, ow1, ob1, ow2, ob2, (float*)d_out);
}

// Round 4
// 586.194 us; speedup vs baseline: 1.3201x; 1.0184x over previous
//
#include <hip/hip_runtime.h>

#define DD 256
#define TWO_D 512
#define NLAYER 5
#define NGRAPH 256
#define BNEPS 1e-5f

typedef __attribute__((ext_vector_type(8))) _Float16 half8;
typedef __attribute__((ext_vector_type(4))) _Float16 half4;
typedef __attribute__((ext_vector_type(4))) float f32x4;
typedef __attribute__((address_space(1))) void gvoid_t;
typedef __attribute__((address_space(3))) void svoid_t;

// ================= fused prep: embed | wconv | etab | zero | pack =================
// role-split by blockIdx.x range; all parts independent.
__global__ __launch_bounds__(256) void prep_kernel(
    const int* __restrict__ xf,
    const float* __restrict__ nt1, const float* __restrict__ nt2,
    const float* __restrict__ nt3, const float* __restrict__ nt4,
    const float* __restrict__ nt5, const float* __restrict__ nt6,
    _Float16* __restrict__ h16,
    const float* __restrict__ w1, const float* __restrict__ w2,
    _Float16* __restrict__ w1h, _Float16* __restrict__ w2h,
    const float* __restrict__ et1, const float* __restrict__ et2,
    const float* __restrict__ et3, const float* __restrict__ et4,
    const float* __restrict__ et5, _Float16* __restrict__ etab,
    int* __restrict__ deg, int* __restrict__ zr, int zr_words,
    const int* __restrict__ ei, const int* __restrict__ ea,
    int* __restrict__ packed,
    int N, int E)
{
  const int t = threadIdx.x;
  const int b = blockIdx.x;
  const int B_EMB = N;
  const int B_WC  = 128;
  const int B_ET  = NLAYER * 33;
  const int B_ZR  = 96;

  if (b < B_EMB) {
    // ---- embedding ----
    int i = b, j = t;
    int x0 = xf[i*6+0], x1 = xf[i*6+1], x2 = xf[i*6+2];
    int x3 = xf[i*6+3], x4 = xf[i*6+4], x5 = xf[i*6+5];
    float v = nt1[x0*DD+j] + nt2[x1*DD+j] + nt3[x2*DD+j]
            + nt4[x3*DD+j] + nt5[x4*DD+j] + nt6[x5*DD+j];
    h16[(size_t)i*DD + j] = (_Float16)v;
  } else if (b < B_EMB + B_WC) {
    // ---- weights -> fp16 ----
    int bid = b - B_EMB;
    int n = NLAYER * TWO_D * DD;
    for (int i = bid*256 + t; i < n; i += B_WC*256) {
      w1h[i] = (_Float16)w1[i];
      w2h[i] = (_Float16)w2[i];
    }
  } else if (b < B_EMB + B_WC + B_ET) {
    // ---- edge-code table ----
    int bid = b - B_EMB - B_WC;
    int l = bid / 33, c = bid % 33;
    int j = t;
    int a0 = (c==32)?4:(c&1);
    int a1 = (c==32)?0:((c>>1)&1);
    int a2 = (c==32)?0:((c>>2)&1);
    int a3 = (c==32)?0:((c>>3)&1);
    int a4 = (c==32)?0:((c>>4)&1);
    etab[((size_t)l*33 + c)*DD + j] = (_Float16)(
        et1[(l*5+a0)*DD+j] + et2[(l*4+a1)*DD+j] + et3[(l*2+a2)*DD+j]
      + et4[(l*2+a3)*DD+j] + et5[(l*2+a4)*DD+j]);
  } else if (b < B_EMB + B_WC + B_ET + B_ZR) {
    // ---- zero deg + stats/hgsum/hgcnt/pstats region ----
    int bid = b - B_EMB - B_WC - B_ET;
    int tw = N + zr_words;
    for (int i = bid*256 + t; i < tw; i += B_ZR*256) {
      if (i < N) deg[i] = 0;
      else zr[i - N] = 0;
    }
  } else {
    // ---- pack edges: src | code<<16 ----
    int bid = b - B_EMB - B_WC - B_ET - B_ZR;
    int e = bid*256 + t;
    if (e < E) {
      int src = ei[e];
      int code = (ea[e*5+0]&1) | ((ea[e*5+1]&1)<<1) | ((ea[e*5+2]&1)<<2)
               | ((ea[e*5+3]&1)<<3) | ((ea[e*5+4]&1)<<4);
      packed[e] = src | (code << 16);
    }
  }
}

// ================= CSR build =================
__global__ __launch_bounds__(256) void hist_kernel(
    const int* __restrict__ ei, int* __restrict__ deg, int E)
{
  int e = blockIdx.x*256 + threadIdx.x;
  if (e < E) atomicAdd(&deg[ei[E + e]], 1);
}

__global__ __launch_bounds__(1024) void scan_kernel(
    const int* __restrict__ deg, int* __restrict__ row_start,
    int* __restrict__ cursor, int N)
{
  __shared__ int sh[1024];
  int t = threadIdx.x;
  const int CH = (N + 1023) >> 10;
  int base = t * CH;
  int lim = N - base; if (lim < 0) lim = 0; if (lim > CH) lim = CH;
  int s = 0;
  for (int i = 0; i < lim; ++i) s += deg[base + i];
  sh[t] = s;
  __syncthreads();
  for (int off = 1; off < 1024; off <<= 1) {
    int x = (t >= off) ? sh[t - off] : 0;
    __syncthreads();
    sh[t] += x;
    __syncthreads();
  }
  int run = t ? sh[t-1] : 0;
  for (int i = 0; i < lim; ++i) {
    row_start[base+i] = run; cursor[base+i] = run;
    run += deg[base+i];
  }
  if (t == 1023) row_start[N] = sh[1023];
}

__global__ __launch_bounds__(256) void scatter_kernel(
    const int* __restrict__ ei, const int* __restrict__ packed,
    int* __restrict__ cursor, int* __restrict__ esort, int E)
{
  int e = blockIdx.x*256 + threadIdx.x;
  if (e >= E) return;
  int dst = ei[E + e];
  int pos = atomicAdd(&cursor[dst], 1);
  esort[pos] = packed[e];
}

// ================= aggregation: one wave per node, inline BN+ReLU =================
// APPLY_BN=1: hsrc is raw pre-BN hh16; sc/sh computed from raw column stats.
template<int APPLY_BN>
__global__ __launch_bounds__(256) void aggr_kernel(
    const _Float16* __restrict__ hsrc, const _Float16* __restrict__ etab_l,
    const int* __restrict__ row_start, const int* __restrict__ esort,
    const float* __restrict__ stats_prev, const float* __restrict__ g,
    const float* __restrict__ bb, float inv_n,
    _Float16* __restrict__ aggrh, int N)
{
  __shared__ __attribute__((aligned(16))) _Float16 se[33*DD];
  for (int i = threadIdx.x; i < 33*DD/8; i += 256)
    ((int4*)se)[i] = ((const int4*)etab_l)[i];
  __syncthreads();
  const int wave = threadIdx.x >> 6, lane = threadIdx.x & 63;
  const int c4 = lane << 2;
  float sc0=1.f, sc1=1.f, sc2=1.f, sc3=1.f, sh0=0.f, sh1=0.f, sh2=0.f, sh3=0.f;
  if (APPLY_BN) {
#define MKSC(k, SC, SH) { float m_ = stats_prev[c4+k]*inv_n;                      \
    float v_ = fmaxf(stats_prev[DD+c4+k]*inv_n - m_*m_, 0.f);                     \
    SC = g[c4+k]*rsqrtf(v_+BNEPS); SH = bb[c4+k] - m_*SC; }
    MKSC(0, sc0, sh0) MKSC(1, sc1, sh1) MKSC(2, sc2, sh2) MKSC(3, sc3, sh3)
#undef MKSC
  }
  const int W0 = blockIdx.x*4 + wave, NW = gridDim.x*4;

#define BNX(h4, o0, o1, o2, o3)                                           \
  { float t0_ = (float)(h4).x, t1_ = (float)(h4).y,                       \
          t2_ = (float)(h4).z, t3_ = (float)(h4).w;                       \
    if (APPLY_BN) {                                                       \
      t0_ = fmaxf(t0_*sc0 + sh0, 0.f); t1_ = fmaxf(t1_*sc1 + sh1, 0.f);  \
      t2_ = fmaxf(t2_*sc2 + sh2, 0.f); t3_ = fmaxf(t3_*sc3 + sh3, 0.f);  \
    }                                                                     \
    o0 = t0_; o1 = t1_; o2 = t2_; o3 = t3_; }

  for (int node = W0; node < N; node += NW) {
    int p  = row_start[node];
    int pe = row_start[node+1];
    const half4 hv = *(const half4*)(hsrc + (size_t)node*DD + c4);
    const half4 sv = *(const half4*)(se + 32*DD + c4);
    float ax, ay, az, aw;
    BNX(hv, ax, ay, az, aw);
    ax += (float)sv.x; ay += (float)sv.y; az += (float)sv.z; aw += (float)sv.w;
    for (; p + 4 <= pe; p += 4) {
      int pk0 = esort[p], pk1 = esort[p+1], pk2 = esort[p+2], pk3 = esort[p+3];
      const half4 h0 = *(const half4*)(hsrc + (size_t)(pk0 & 0xffff)*DD + c4);
      const half4 h1 = *(const half4*)(hsrc + (size_t)(pk1 & 0xffff)*DD + c4);
      const half4 h2 = *(const half4*)(hsrc + (size_t)(pk2 & 0xffff)*DD + c4);
      const half4 h3 = *(const half4*)(hsrc + (size_t)(pk3 & 0xffff)*DD + c4);
      const half4 e0 = *(const half4*)(se + (pk0 >> 16)*DD + c4);
      const half4 e1 = *(const half4*)(se + (pk1 >> 16)*DD + c4);
      const half4 e2 = *(const half4*)(se + (pk2 >> 16)*DD + c4);
      const half4 e3 = *(const half4*)(se + (pk3 >> 16)*DD + c4);
      float b0x,b0y,b0z,b0w, b1x,b1y,b1z,b1w, b2x,b2y,b2z,b2w, b3x,b3y,b3z,b3w;
      BNX(h0, b0x,b0y,b0z,b0w); BNX(h1, b1x,b1y,b1z,b1w);
      BNX(h2, b2x,b2y,b2z,b2w); BNX(h3, b3x,b3y,b3z,b3w);
      ax += (b0x+(float)e0.x) + (b1x+(float)e1.x) + (b2x+(float)e2.x) + (b3x+(float)e3.x);
      ay += (b0y+(float)e0.y) + (b1y+(float)e1.y) + (b2y+(float)e2.y) + (b3y+(float)e3.y);
      az += (b0z+(float)e0.z) + (b1z+(float)e1.z) + (b2z+(float)e2.z) + (b3z+(float)e3.z);
      aw += (b0w+(float)e0.w) + (b1w+(float)e1.w) + (b2w+(float)e2.w) + (b3w+(float)e3.w);
    }
    for (; p < pe; ++p) {
      int pk = esort[p];
      const half4 hx = *(const half4*)(hsrc + (size_t)(pk & 0xffff)*DD + c4);
      const half4 ex = *(const half4*)(se + (pk >> 16)*DD + c4);
      float bx, by, bz, bw;
      BNX(hx, bx, by, bz, bw);
      ax += bx + (float)ex.x; ay += by + (float)ex.y;
      az += bz + (float)ex.z; aw += bw + (float)ex.w;
    }
    half4 o;
    o.x = (_Float16)ax; o.y = (_Float16)ay; o.z = (_Float16)az; o.w = (_Float16)aw;
    *(half4*)(aggrh + (size_t)node*DD + c4) = o;
  }
#undef BNX
}

// ================= fp16 MFMA GEMM with LDS-transpose epilogue =================
// C[M,Nw] = A[M,K]*B[Nw,K]^T + bias. RELU: relu before store. STATS: column sums
// (rows < Nreal) into stats. Output fp16, stored as dwordx4 via LDS transpose.
template<int RELU, int STATS>
__global__ __launch_bounds__(256) void gemm_bt(
    const _Float16* __restrict__ A,
    const _Float16* __restrict__ B,
    const float* __restrict__ bias,
    _Float16* __restrict__ O,
    float* __restrict__ stats,
    int K, int Nw, int Nreal)
{
  __shared__ __attribute__((aligned(16))) _Float16 smem[8192];  // 16 KB
  _Float16* lA = smem;          // 128x32
  _Float16* lB = smem + 4096;   // 128x32
  const int NT = Nw >> 7;
  const int bm = blockIdx.x / NT, bn = blockIdx.x % NT;
  const int m0 = bm << 7, n0 = bn << 7;
  const int t = threadIdx.x;
  const int wave = t >> 6, lane = t & 63;
  const int wm = wave & 1, wn = wave >> 1;
  const int r15 = lane & 15, quad = lane >> 4;
  const int srow = lane >> 2, sq = (lane & 3) << 3;
  f32x4 acc[4][4] = {};
  for (int k0 = 0; k0 < K; k0 += 32) {
    __syncthreads();
#pragma unroll
    for (int i = 0; i < 2; ++i) {
      const int seg = wave*2 + i;
      const int row = seg*16 + srow;
      __builtin_amdgcn_global_load_lds((gvoid_t*)(A + (size_t)(m0+row)*K + k0 + sq),
                                       (svoid_t*)(lA + seg*512), 16, 0, 0);
      __builtin_amdgcn_global_load_lds((gvoid_t*)(B + (size_t)(n0+row)*K + k0 + sq),
                                       (svoid_t*)(lB + seg*512), 16, 0, 0);
    }
    __syncthreads();
    half8 af[4], bfr[4];
#pragma unroll
    for (int f = 0; f < 4; ++f) {
      af[f]  = *(const half8*)(lA + (((wm<<6) + (f<<4) + r15) << 5) + (quad<<3));
      bfr[f] = *(const half8*)(lB + (((wn<<6) + (f<<4) + r15) << 5) + (quad<<3));
    }
#pragma unroll
    for (int fm = 0; fm < 4; ++fm)
#pragma unroll
      for (int fn = 0; fn < 4; ++fn)
        acc[fm][fn] = __builtin_amdgcn_mfma_f32_16x16x32_f16(af[fm], bfr[fn], acc[fm][fn], 0, 0, 0);
  }
  // -------- epilogue: bias(+relu)(+stats), LDS transpose, vector stores --------
  float bv[4];
#pragma unroll
  for (int fn = 0; fn < 4; ++fn) bv[fn] = bias[n0 + (wn<<6) + (fn<<4) + r15];
  __syncthreads();   // all ds_reads of staging done before overwrite
  _Float16* tb = smem;  // 128 rows x pitch 40 halfs (5120 <= 8192)
#pragma unroll
  for (int fn = 0; fn < 4; ++fn) {
    float s1 = 0.f, s2 = 0.f;
#pragma unroll
    for (int fm = 0; fm < 4; ++fm) {
      const int lr = (wm<<6) + (fm<<4) + (quad<<2);
#pragma unroll
      for (int r = 0; r < 4; ++r) {
        float v = acc[fm][fn][r] + bv[fn];
        if (RELU) v = fmaxf(v, 0.f);
        tb[(lr + r)*40 + (wn<<4) + r15] = (_Float16)v;
        if (STATS && (m0 + lr + r < Nreal)) { s1 += v; s2 += v*v; }
      }
    }
    if (STATS) {
      s1 += __shfl_xor(s1, 16); s1 += __shfl_xor(s1, 32);
      s2 += __shfl_xor(s2, 16); s2 += __shfl_xor(s2, 32);
      if (lane < 16) {
        const int col = n0 + (wn<<6) + (fn<<4) + r15;
        atomicAdd(&stats[col], s1); atomicAdd(&stats[DD + col], s2);
      }
    }
    __syncthreads();
#pragma unroll
    for (int it = 0; it < 2; ++it) {
      int p = t + (it << 8);
      int row = p & 127, strip = (p >> 7) & 1, hsel = p >> 8;
      half8 vv = *(const half8*)(tb + row*40 + (strip<<4) + (hsel<<3));
      *(half8*)(O + (size_t)(m0+row)*Nw + n0 + (strip<<6) + (fn<<4) + (hsel<<3)) = vv;
    }
    __syncthreads();
  }
}

// ================= mean pool by (sorted) batch, inline BN+ReLU =================
__global__ __launch_bounds__(256) void pool_kernel(
    const _Float16* __restrict__ hh16, const float* __restrict__ stats_prev,
    const float* __restrict__ g, const float* __restrict__ bb, float inv_n,
    const int* __restrict__ batch,
    float* __restrict__ hgsum, int* __restrict__ hgcnt, int N)
{
  int j = threadIdx.x;
  float m = stats_prev[j]*inv_n;
  float var = fmaxf(stats_prev[DD+j]*inv_n - m*m, 0.f);
  float sc = g[j]*rsqrtf(var + BNEPS);
  float sh = bb[j] - m*sc;
  int r0 = blockIdx.x * 64;
  int cur = -1; float acc = 0.f; int run = 0;
  for (int r = 0; r < 64; ++r) {
    int row = r0 + r;
    if (row >= N) break;
    int gg = batch[row];
    if (gg != cur) {
      if (cur >= 0) {
        atomicAdd(&hgsum[(size_t)cur*DD + j], acc);
        if (j == 0) atomicAdd(&hgcnt[cur], run);
      }
      cur = gg; acc = 0.f; run = 0;
    }
    float v = (float)hh16[(size_t)row*DD + j];
    acc += fmaxf(v*sc + sh, 0.f);
    run++;
  }
  if (cur >= 0) {
    atomicAdd(&hgsum[(size_t)cur*DD + j], acc);
    if (j == 0) atomicAdd(&hgcnt[cur], run);
  }
}

// ================= projection head GEMM with fused input transform =================
// MODE 0: A = hgsum/cnt (mean-pool finish).  MODE 1: A = relu(bn(in)) from prev stats.
template<int MODE>
__global__ __launch_bounds__(256) void proj_gemm_kernel(
    const float* __restrict__ in, const int* __restrict__ cnt,
    const float* __restrict__ pstat_prev,
    const float* __restrict__ gprev, const float* __restrict__ bprev,
    const float* __restrict__ W,
    float* __restrict__ outb, float* __restrict__ pstat)
{
  __shared__ float sA[16][17];
  __shared__ float sB[16][17];
  int tx = threadIdx.x, ty = threadIdx.y;
  int r = blockIdx.y*16 + ty;
  int c = blockIdx.x*16 + tx;
  float acc = 0.f;
  for (int k0 = 0; k0 < DD; k0 += 16) {
    int k = k0 + tx;
    float a = in[(size_t)r*DD + k];
    if (MODE == 0) {
      a /= (float)max(cnt[r], 1);
    } else {
      float m = pstat_prev[k] * (1.0f/NGRAPH);
      float var = fmaxf(pstat_prev[DD + k] * (1.0f/NGRAPH) - m*m, 0.f);
      float sc = gprev[k] * rsqrtf(var + BNEPS);
      a = fmaxf((a - m)*sc + bprev[k], 0.f);
    }
    sA[ty][tx] = a;
    sB[ty][tx] = W[(size_t)(blockIdx.x*16 + ty)*DD + k0 + tx];
    __syncthreads();
#pragma unroll
    for (int kk = 0; kk < 16; ++kk) acc += sA[ty][kk] * sB[tx][kk];
    __syncthreads();
  }
  outb[(size_t)r*DD + c] = acc;
  sA[ty][tx] = acc; sB[ty][tx] = acc*acc;
  __syncthreads();
  for (int o = 8; o > 0; o >>= 1) {
    if (ty < o) { sA[ty][tx] += sA[ty+o][tx]; sB[ty][tx] += sB[ty+o][tx]; }
    __syncthreads();
  }
  if (ty == 0) { atomicAdd(&pstat[c], sA[0][tx]); atomicAdd(&pstat[DD + c], sB[0][tx]); }
}

// ================= output MLP with fused final BN (no relu) =================
__global__ __launch_bounds__(128) void out_kernel(
    const float* __restrict__ t2, const float* __restrict__ pstat2,
    const float* __restrict__ g2, const float* __restrict__ b2p,
    const float* __restrict__ ow1, const float* __restrict__ ob1,
    const float* __restrict__ ow2, const float* __restrict__ ob2,
    float* __restrict__ outp)
{
  __shared__ float rowv[DD];
  __shared__ float z[128];
  int r = blockIdx.x, t = threadIdx.x;
#pragma unroll
  for (int half = 0; half < 2; ++half) {
    int j = t + half*128;
    float m = pstat2[j] * (1.0f/NGRAPH);
    float var = fmaxf(pstat2[DD + j] * (1.0f/NGRAPH) - m*m, 0.f);
    float sc = g2[j] * rsqrtf(var + BNEPS);
    rowv[j] = (t2[(size_t)r*DD + j] - m)*sc + b2p[j];
  }
  __syncthreads();
  float a = ob1[t];
  for (int k = 0; k < DD; ++k) a += rowv[k] * ow1[(size_t)t*DD + k];
  z[t] = fmaxf(a, 0.f) + log1pf(expf(-fabsf(a)));   // softplus, stable
  __syncthreads();
  if (t < 2) {
    float o = ob2[t];
    for (int k = 0; k < 128; ++k) o += z[k] * ow2[t*128 + k];
    outp[r*2 + t] = o;
  }
}

// ================= host launcher =================
extern "C" void kernel_launch(void* const* d_in, const int* in_sizes, int n_in,
                              void* d_out, int out_size, void* d_ws, size_t ws_size,
                              hipStream_t stream)
{
  const int* x_feats = (const int*)d_in[0];
  const int* ei      = (const int*)d_in[1];
  const int* ea      = (const int*)d_in[2];
  const int* batch   = (const int*)d_in[3];
  const float* nt1 = (const float*)d_in[4];
  const float* nt2 = (const float*)d_in[5];
  const float* nt3 = (const float*)d_in[6];
  const float* nt4 = (const float*)d_in[7];
  const float* nt5 = (const float*)d_in[8];
  const float* nt6 = (const float*)d_in[9];
  const float* et1 = (const float*)d_in[10];
  const float* et2 = (const float*)d_in[11];
  const float* et3 = (const float*)d_in[12];
  const float* et4 = (const float*)d_in[13];
  const float* et5 = (const float*)d_in[14];
  const float* w1  = (const float*)d_in[15];
  const float* b1  = (const float*)d_in[16];
  const float* w2  = (const float*)d_in[17];
  const float* b2  = (const float*)d_in[18];
  const float* bng = (const float*)d_in[19];
  const float* bnb = (const float*)d_in[20];
  const float* pw  = (const float*)d_in[21];
  const float* pg  = (const float*)d_in[22];
  const float* pb  = (const float*)d_in[23];
  const float* ow1 = (const float*)d_in[24];
  const float* ob1 = (const float*)d_in[25];
  const float* ow2 = (const float*)d_in[26];
  const float* ob2 = (const float*)d_in[27];

  const int N = in_sizes[0] / 6;        // 20000
  const int E = in_sizes[1] / 2;        // 320000
  const int Mp = ((N + 127) >> 7) << 7; // 20096

  unsigned char* wp = (unsigned char*)d_ws;
  size_t off = 0;
  auto carve = [&](size_t bytes) -> void* {
    void* p = wp + off;
    off += (bytes + 255) & ~(size_t)255;
    return p;
  };

  _Float16* h16      = (_Float16*)carve((size_t)N * DD * 2);
  _Float16* aggrh    = (_Float16*)carve((size_t)Mp * DD * 2);
  _Float16* hh16     = (_Float16*)carve((size_t)Mp * DD * 2);
  _Float16* hidh     = (_Float16*)carve((size_t)Mp * TWO_D * 2);
  _Float16* w1h      = (_Float16*)carve((size_t)NLAYER * TWO_D * DD * 2);
  _Float16* w2h      = (_Float16*)carve((size_t)NLAYER * TWO_D * DD * 2);
  _Float16* etabg    = (_Float16*)carve((size_t)NLAYER * 33 * DD * 2);
  int* deg           = (int*)carve((size_t)N * 4);
  int* row_start     = (int*)carve((size_t)(N + 1) * 4);
  int* cursor        = (int*)carve((size_t)N * 4);
  int* packed        = (int*)carve((size_t)E * 4);
  int* esort         = (int*)carve((size_t)E * 4);
  // ---- contiguous zero region (each carve size is a multiple of 256 B) ----
  float* stats       = (float*)carve((size_t)NLAYER * 2 * DD * 4);  // per-layer BN stats
  float* hgsum       = (float*)carve((size_t)NGRAPH * DD * 4);
  int* hgcnt         = (int*)carve((size_t)NGRAPH * 4);
  float* pstats      = (float*)carve(3 * 2 * DD * 4);
  const int ZR_WORDS = NLAYER*2*DD + NGRAPH*DD + NGRAPH + 3*2*DD;
  // ---- end zero region ----
  float* hgA         = (float*)carve((size_t)NGRAPH * DD * 4);
  float* hgB         = (float*)carve((size_t)NGRAPH * DD * 4);
  float* t0c         = (float*)carve((size_t)NGRAPH * DD * 4);
  (void)ws_size; (void)n_in; (void)out_size;

  const int EB = (E + 255) / 256;
  const float inv_n = 1.0f / (float)N;

  // ---- prep: embed | wconv | etab | zero | pack (one dispatch) ----
  const int PREP_BLOCKS = N + 128 + NLAYER*33 + 96 + EB;
  prep_kernel<<<PREP_BLOCKS, 256, 0, stream>>>(
      x_feats, nt1, nt2, nt3, nt4, nt5, nt6, h16,
      w1, w2, w1h, w2h,
      et1, et2, et3, et4, et5, etabg,
      deg, (int*)stats, ZR_WORDS,
      ei, ea, packed, N, E);
  hist_kernel<<<EB, 256, 0, stream>>>(ei, deg, E);
  scan_kernel<<<1, 1024, 0, stream>>>(deg, row_start, cursor, N);
  scatter_kernel<<<EB, 256, 0, stream>>>(ei, packed, cursor, esort, E);

  const int gm = Mp >> 7;
  for (int l = 0; l < NLAYER; ++l) {
    float* st_prev = stats + (size_t)(l-1)*2*DD;
    float* st_cur  = stats + (size_t)l*2*DD;
    if (l == 0) {
      aggr_kernel<0><<<2048, 256, 0, stream>>>(h16, etabg, row_start, esort,
                                               nullptr, nullptr, nullptr, inv_n,
                                               aggrh, N);
    } else {
      aggr_kernel<1><<<2048, 256, 0, stream>>>(hh16, etabg + (size_t)l*33*DD,
                                               row_start, esort,
                                               st_prev, bng + (l-1)*DD, bnb + (l-1)*DD,
                                               inv_n, aggrh, N);
    }
    gemm_bt<1,0><<<gm * (TWO_D >> 7), 256, 0, stream>>>(
        aggrh, w1h + (size_t)l*TWO_D*DD, b1 + l*TWO_D, hidh, nullptr,
        DD, TWO_D, N);
    gemm_bt<0,1><<<gm * (DD >> 7), 256, 0, stream>>>(
        hidh, w2h + (size_t)l*DD*TWO_D, b2 + l*DD, hh16, st_cur,
        TWO_D, DD, N);
  }

  // ---- tail: pool(+BN4) -> pg0(/cnt) -> pg1(+bn0,relu) -> pg2(+bn1,relu) -> out(+bn2) ----
  pool_kernel<<<(N + 63) / 64, 256, 0, stream>>>(
      hh16, stats + (size_t)(NLAYER-1)*2*DD, bng + (NLAYER-1)*DD, bnb + (NLAYER-1)*DD,
      inv_n, batch, hgsum, hgcnt, N);

  dim3 pgrid(16, 16), pblk(16, 16);
  proj_gemm_kernel<0><<<pgrid, pblk, 0, stream>>>(
      hgsum, hgcnt, nullptr, nullptr, nullptr,
      pw + 0*DD*DD, hgA, pstats + 0*2*DD);
  proj_gemm_kernel<1><<<pgrid, pblk, 0, stream>>>(
      hgA, nullptr, pstats + 0*2*DD, pg + 0*DD, pb + 0*DD,
      pw + 1*DD*DD, hgB, pstats + 1*2*DD);
  proj_gemm_kernel<1><<<pgrid, pblk, 0, stream>>>(
      hgB, nullptr, pstats + 1*2*DD, pg + 1*DD, pb + 1*DD,
      pw + 2*DD*DD, t0c, pstats + 2*2*DD);
  out_kernel<<<NGRAPH, 128, 0, stream>>>(
      t0c, pstats + 2*2*DD, pg + 2*DD, pb + 2*DD,
      ow1, ob1, ow2, ob2, (float*)d_out);
}